// Round 12
// baseline (957.936 us; speedup 1.0000x reference)
//
#include <hip/hip_runtime.h>
#include <hip/hip_bf16.h>

#define BATCH  4096
#define NCC    64
#define HDIM   256
#define G3     768
#define NROW   (BATCH*NCC)   // 262144
#define NK     20
#define LOG2PI 1.8378770664093453f

typedef __attribute__((ext_vector_type(8))) short bf16x8;
typedef __attribute__((ext_vector_type(4))) float f32x4;

__device__ __forceinline__ float sigm(float x) { return 1.0f/(1.0f + __expf(-x)); }
__device__ __forceinline__ float tanh_fast(float x) { return 1.0f - 2.0f/(__expf(2.0f*x) + 1.0f); }
__device__ __forceinline__ unsigned short f2bf(float x) {
  __hip_bfloat16 h = __float2bfloat16(x);
  return __builtin_bit_cast(unsigned short, h);
}
__device__ __forceinline__ float bf2f(unsigned short u) {
  unsigned int v = ((unsigned int)u) << 16;
  return __builtin_bit_cast(float, v);
}
__device__ __forceinline__ int swz(int r) { return (r & 7) ^ ((r & 8) >> 2); }

// ---- one elementwise pass: build cbmB, CW, WhhB, W1aB, W2B, W3pB, w0 ----
__global__ __launch_bounds__(256) void k_cvtall(
    const float* __restrict__ c, const float* __restrict__ bv,
    const float* __restrict__ mv, const float* __restrict__ W_ih,
    const float* __restrict__ W_hh, const float* __restrict__ W1,
    const float* __restrict__ W2, const float* __restrict__ W3,
    unsigned short* __restrict__ cbmB, unsigned short* __restrict__ CW,
    unsigned short* __restrict__ WhhB, unsigned short* __restrict__ W1aB,
    unsigned short* __restrict__ W2B, unsigned short* __restrict__ W3pB,
    float* __restrict__ w0) {
  int idx = blockIdx.x*256 + threadIdx.x;
  if (idx < 1048576) {            // cbmB [4096][256], K-padded
    int row = idx >> 8, k = idx & 255;
    float v = 0.f;
    if (k < 80)       v = c [row*80 + k];
    else if (k < 144) v = bv[row*64 + (k-80)];
    else if (k < 208) v = mv[row*64 + (k-144)];
    cbmB[idx] = f2bf(v);
    return;
  }
  idx -= 1048576;
  if (idx < 262144) {             // CW [1024][256]: W_ih cols 1.. | W1 cols 256..
    int n = idx >> 8, k = idx & 255;
    float v = 0.f;
    if (n < 768) { if (k < 208) v = W_ih[n*209 + 1 + k]; }
    else         { if (k < 208) v = W1[(n-768)*464 + 256 + k]; }
    CW[idx] = f2bf(v);
    return;
  }
  idx -= 262144;
  if (idx < 196608) { WhhB[idx] = f2bf(W_hh[idx]); return; }
  idx -= 196608;
  if (idx < 65536) { int n = idx>>8, k = idx&255; W1aB[idx] = f2bf(W1[n*464+k]); return; }
  idx -= 65536;
  if (idx < 65536) { W2B[idx] = f2bf(W2[idx]); return; }
  idx -= 65536;
  if (idx < 16384) {
    int n = idx >> 8;
    float v = 0.f;
    if (n < 60) v = W3[idx];
    W3pB[idx] = f2bf(v);
    return;
  }
  idx -= 16384;
  if (idx < 768) w0[idx] = W_ih[idx*209];
}

// ---- pre-GEMM: [4096 x 1024 x 256(pad)] -> gi (+biases) / P1 (+b1) ----
__global__ __launch_bounds__(512) void k_pre(
    const unsigned short* __restrict__ A, const unsigned short* __restrict__ Bw,
    const float* __restrict__ b_ih, const float* __restrict__ b_hh,
    const float* __restrict__ b1,
    float* __restrict__ gi, float* __restrict__ P1) {
  __shared__ __align__(16) unsigned short As[128*64];
  __shared__ __align__(16) unsigned short Bs[128*64];
  int tid = threadIdx.x;
  int rb = blockIdx.x >> 3, cb = blockIdx.x & 7;
  long row0 = (long)rb * 128;
  int n0 = cb * 128;
  int wv = tid >> 6, lane = tid & 63;
  int lq = lane >> 4, l16 = lane & 15;
  int wrg = wv & 3, wcg = wv >> 2;
  f32x4 acc[2][4];
#pragma unroll
  for (int i = 0; i < 2; ++i)
#pragma unroll
    for (int j = 0; j < 4; ++j) acc[i][j] = (f32x4){0.f,0.f,0.f,0.f};
  for (int kb = 0; kb < 256; kb += 64) {
#pragma unroll
    for (int i = 0; i < 2; ++i) {
      int s = i*512 + tid;
      int r = s >> 3, cg = (s & 7) ^ (r & 7);
      *(uint4*)&As[s*8] = *(const uint4*)&A[(row0 + r)*256 + kb + cg*8];
      *(uint4*)&Bs[s*8] = *(const uint4*)&Bw[(long)(n0 + r)*256 + kb + cg*8];
    }
    __syncthreads();
#pragma unroll
    for (int kc = 0; kc < 2; ++kc) {
      int csel = kc*4 + lq;
      bf16x8 af[2];
#pragma unroll
      for (int rt = 0; rt < 2; ++rt) {
        int r = wrg*32 + rt*16 + l16;
        af[rt] = *(const bf16x8*)&As[r*64 + ((csel ^ (r & 7)))*8];
      }
#pragma unroll
      for (int ct = 0; ct < 4; ++ct) {
        int n = wcg*64 + ct*16 + l16;
        bf16x8 bfr = *(const bf16x8*)&Bs[n*64 + ((csel ^ (n & 7)))*8];
        acc[0][ct] = __builtin_amdgcn_mfma_f32_16x16x32_bf16(af[0], bfr, acc[0][ct], 0, 0, 0);
        acc[1][ct] = __builtin_amdgcn_mfma_f32_16x16x32_bf16(af[1], bfr, acc[1][ct], 0, 0, 0);
      }
    }
    __syncthreads();
  }
#pragma unroll
  for (int rt = 0; rt < 2; ++rt)
#pragma unroll
    for (int q = 0; q < 4; ++q) {
      long row = row0 + wrg*32 + rt*16 + lq*4 + q;
#pragma unroll
      for (int ct = 0; ct < 4; ++ct) {
        int n = n0 + wcg*64 + ct*16 + l16;
        float v = acc[rt][ct][q];
        if (n < 512)      gi[row*G3 + n] = v + b_ih[n] + b_hh[n];
        else if (n < 768) gi[row*G3 + n] = v + b_ih[n];
        else              P1[row*256 + (n-768)] = v + b1[n-768];
      }
    }
}

// ---- persistent GRU v4: 128 blocks x 32 rows, 1024 threads (16 waves) ----
// Design for STREAMING (R7-R11: compiler refuses to keep weight frags
// resident). B-fragments load straight from global each step (L2-cached,
// t-invariant addresses); 32 rows/block halves per-XCD L2 traffic vs 16
// (12.6 -> 6.3 MB/XCD-step ~= 93 us) and overlaps the ~99 us MFMA floor.
// Live regs ~85: fits even the allocator's stingiest (64-reg) target.
__global__ __attribute__((amdgpu_flat_work_group_size(1024, 1024)))
void k_gru(
    const float* __restrict__ z, const float* __restrict__ gi,
    const unsigned short* __restrict__ WhhB, const float* __restrict__ b_hh,
    const float* __restrict__ w0, unsigned short* __restrict__ hs) {
  __shared__ __align__(16) unsigned short hbf[2*32*256];  // 32 KB h dbuf
  __shared__ __align__(16) unsigned short gis[768*36];    // 54 KB gi^T bf16, stride 36
  __shared__ __align__(16) float zs[64*32];               // 8 KB z^T [t][row]
  __shared__ float wls[1024];                             // 4 KB w0 | b_hh_n
  int tid = threadIdx.x;
  int wv = tid >> 6, lane = tid & 63;
  int lq = lane >> 4, l16 = lane & 15;
  int row0 = blockIdx.x * 32;
  const int hc = wv*16 + l16;          // this lane's h-col
  // t-invariant B-fragment base pointers (one per gate)
  const unsigned short* bp0 = WhhB + (long)(         hc)*256 + lq*8;
  const unsigned short* bp1 = WhhB + (long)(256 +    hc)*256 + lq*8;
  const unsigned short* bp2 = WhhB + (long)(512 +    hc)*256 + lq*8;
  // stage w0 (768) + b_hh n-gate (256)
  if (tid < 768) wls[tid] = w0[tid];
  else           wls[tid] = b_hh[512 + (tid - 768)];
  // stage z transposed: zs[t*32 + r]
  for (int i = tid; i < 2048; i += 1024) {
    int t = i >> 5, r = i & 31;
    zs[i] = z[(row0 + r)*64 + t];
  }
  // stage gi slice transposed to bf16: gis[cc*36 + r]
#pragma unroll
  for (int i = 0; i < 24; ++i) {
    int s = i*1024 + tid;              // 24576 elements
    int r = s / 768, cc = s - r*768;
    gis[cc*36 + r] = f2bf(gi[(long)(row0 + r)*768 + cc]);
  }
  for (int i = tid; i < 4096; i += 1024) ((unsigned int*)hbf)[i] = 0u;  // zero buf0
  float hp[2][4] = {{0.f,0.f,0.f,0.f},{0.f,0.f,0.f,0.f}};
  const int s7 = l16 & 7;
  const int r4 = lq*4;
  // copy-out mapping: thread -> (row cr, chunk ccc), 16 B each
  const int cr = tid >> 5, ccc = tid & 31;
  const int csrc = cr*256 + ((ccc ^ (cr & 7)))*8;
  unsigned short* cbase = hs + (long)(row0 + cr)*64*256 + ccc*8;
  __syncthreads();
#pragma unroll 1
  for (int t = 0; t < 64; ++t) {
    const int co = (t & 1) << 13;      // current buffer offset (shorts, 8192)
    const int no = co ^ 8192;          // next buffer offset
    // C-init: gi^T (bf16->f32) + rank-1 z; n-gate C = b_hh_n
    f32x4 a[6];                        // [gate*2 + rt]
    float zp[2][4];
    {
      float w0r = wls[hc], w0u = wls[256+hc], bn = wls[768+hc];
      int tm = (t ? (t-1) : 0)*32;
#pragma unroll
      for (int rt = 0; rt < 2; ++rt) {
        float4 zv4 = *(const float4*)&zs[tm + rt*16 + r4];
        const unsigned short* gb = &gis[hc*36 + rt*16 + r4];
#pragma unroll
        for (int q = 0; q < 4; ++q) {
          float zpv = t ? (&zv4.x)[q] : -1.0f;
          zp[rt][q] = zpv;
          a[rt][q]   = bf2f(gb[q + 0*(256*36 - 0)]) + zpv*w0r; // gR
          a[2+rt][q] = bf2f(gis[(256+hc)*36 + rt*16 + r4 + q]) + zpv*w0u;
          a[4+rt][q] = bn;
        }
      }
    }
    // K loop: A from LDS, B streamed from global (L2)
#pragma unroll
    for (int ks = 0; ks < 8; ++ks) {
      bf16x8 b0 = *(const bf16x8*)(bp0 + ks*32);
      bf16x8 b1 = *(const bf16x8*)(bp1 + ks*32);
      bf16x8 b2 = *(const bf16x8*)(bp2 + ks*32);
#pragma unroll
      for (int rt = 0; rt < 2; ++rt) {
        int r = rt*16 + l16;
        bf16x8 af = *(const bf16x8*)&hbf[co + r*256 + (((ks*4+lq) ^ (r & 7)))*8];
        a[rt]   = __builtin_amdgcn_mfma_f32_16x16x32_bf16(af, b0, a[rt],   0, 0, 0);
        a[2+rt] = __builtin_amdgcn_mfma_f32_16x16x32_bf16(af, b1, a[2+rt], 0, 0, 0);
        a[4+rt] = __builtin_amdgcn_mfma_f32_16x16x32_bf16(af, b2, a[4+rt], 0, 0, 0);
      }
    }
    if (t) {                            // h_{t-1} copy-out (coalesced 16B)
      uint4 cd = *(const uint4*)&hbf[co + csrc];
      *(uint4*)(cbase + (t-1)*256) = cd;
    }
    // epilogue: h_t = u*(h_{t-1}-n)+n -> next buffer
    {
      float w0n = wls[512+hc];
      int hchunk = hc >> 3, hlow = hc & 7;
#pragma unroll
      for (int rt = 0; rt < 2; ++rt) {
#pragma unroll
        for (int q = 0; q < 4; ++q) {
          int lr = rt*16 + r4 + q;
          float rr = sigm(a[rt][q]);
          float uu = sigm(a[2+rt][q]);
          float gn = bf2f(gis[(512+hc)*36 + lr]);
          float nn = tanh_fast(gn + zp[rt][q]*w0n + rr*a[4+rt][q]);
          float hn = uu*(hp[rt][q] - nn) + nn;
          hp[rt][q] = hn;
          hbf[no + lr*256 + ((hchunk ^ (lr & 7)))*8 + hlow] = f2bf(hn);
        }
      }
    }
    __syncthreads();
  }
  // h_63 lives in buffer 0
  uint4 cd = *(const uint4*)&hbf[0 + csrc];
  *(uint4*)(cbase + 63*256) = cd;
}

// ---- MLP layer 1, in-place: Out = tanh(A @ W1a^T + P1[row>>6]) ----
__global__ __launch_bounds__(512) void k_l1(
    const unsigned short* __restrict__ A, const unsigned short* __restrict__ Bw,
    const float* __restrict__ P1, unsigned short* __restrict__ Out) {
  __shared__ __align__(16) unsigned short As[128*64];
  __shared__ __align__(16) unsigned short Bs[256*64];
  int tid = threadIdx.x;
  long row0 = (long)blockIdx.x * 128;
  int wv = tid >> 6, lane = tid & 63;
  int lq = lane >> 4, l16 = lane & 15;
  int wrg = wv & 3, wcg = wv >> 2;
  f32x4 acc[2][8];
#pragma unroll
  for (int i = 0; i < 2; ++i)
#pragma unroll
    for (int j = 0; j < 8; ++j) acc[i][j] = (f32x4){0.f,0.f,0.f,0.f};
  for (int kb = 0; kb < 256; kb += 64) {
#pragma unroll
    for (int i = 0; i < 2; ++i) {
      int s = i*512 + tid;
      int r = s >> 3, cg = (s & 7) ^ (r & 7);
      *(uint4*)&As[s*8] = *(const uint4*)&A[(row0 + r)*256 + kb + cg*8];
    }
#pragma unroll
    for (int i = 0; i < 4; ++i) {
      int s = i*512 + tid;
      int r = s >> 3, cg = (s & 7) ^ (r & 7);
      *(uint4*)&Bs[s*8] = *(const uint4*)&Bw[(long)r*256 + kb + cg*8];
    }
    __syncthreads();
#pragma unroll
    for (int kc = 0; kc < 2; ++kc) {
      int csel = kc*4 + lq;
      bf16x8 af[2];
#pragma unroll
      for (int rt = 0; rt < 2; ++rt) {
        int r = wrg*32 + rt*16 + l16;
        af[rt] = *(const bf16x8*)&As[r*64 + ((csel ^ (r & 7)))*8];
      }
#pragma unroll
      for (int ct = 0; ct < 8; ++ct) {
        int n = wcg*128 + ct*16 + l16;
        bf16x8 bfr = *(const bf16x8*)&Bs[n*64 + ((csel ^ (n & 7)))*8];
        acc[0][ct] = __builtin_amdgcn_mfma_f32_16x16x32_bf16(af[0], bfr, acc[0][ct], 0, 0, 0);
        acc[1][ct] = __builtin_amdgcn_mfma_f32_16x16x32_bf16(af[1], bfr, acc[1][ct], 0, 0, 0);
      }
    }
    __syncthreads();
  }
#pragma unroll
  for (int rt = 0; rt < 2; ++rt)
#pragma unroll
    for (int q = 0; q < 4; ++q) {
      long row = row0 + wrg*32 + rt*16 + lq*4 + q;
#pragma unroll
      for (int ct = 0; ct < 8; ++ct) {
        int n = wcg*128 + ct*16 + l16;
        float b = P1[(row >> 6)*256 + n];
        Out[row*256 + n] = f2bf(tanh_fast(acc[rt][ct][q] + b));
      }
    }
}

// ---- fused MLP layer2 + layer3 + mixture likelihood ----
__global__ __launch_bounds__(512) void k_l23(
    const unsigned short* __restrict__ A, const unsigned short* __restrict__ W2B,
    const float* __restrict__ b2, const unsigned short* __restrict__ W3pB,
    const float* __restrict__ b3, const float* __restrict__ z,
    float* __restrict__ ll) {
  __shared__ __align__(16) unsigned short As[128*64];
  __shared__ __align__(16) unsigned short Bs[256*64];
  __shared__ __align__(16) unsigned short h2s[128*256];
  int tid = threadIdx.x;
  long row0 = (long)blockIdx.x * 128;
  int wv = tid >> 6, lane = tid & 63;
  int lq = lane >> 4, l16 = lane & 15;
  int wrg = wv & 3, wcg = wv >> 2;
  f32x4 acc[2][8];
#pragma unroll
  for (int i = 0; i < 2; ++i)
#pragma unroll
    for (int j = 0; j < 8; ++j) acc[i][j] = (f32x4){0.f,0.f,0.f,0.f};
  for (int kb = 0; kb < 256; kb += 64) {
#pragma unroll
    for (int i = 0; i < 2; ++i) {
      int s = i*512 + tid;
      int r = s >> 3, cg = (s & 7) ^ (r & 7);
      *(uint4*)&As[s*8] = *(const uint4*)&A[(row0 + r)*256 + kb + cg*8];
    }
#pragma unroll
    for (int i = 0; i < 4; ++i) {
      int s = i*512 + tid;
      int r = s >> 3, cg = (s & 7) ^ (r & 7);
      *(uint4*)&Bs[s*8] = *(const uint4*)&W2B[(long)r*256 + kb + cg*8];
    }
    __syncthreads();
#pragma unroll
    for (int kc = 0; kc < 2; ++kc) {
      int csel = kc*4 + lq;
      bf16x8 af[2];
#pragma unroll
      for (int rt = 0; rt < 2; ++rt) {
        int r = wrg*32 + rt*16 + l16;
        af[rt] = *(const bf16x8*)&As[r*64 + ((csel ^ (r & 7)))*8];
      }
#pragma unroll
      for (int ct = 0; ct < 8; ++ct) {
        int n = wcg*128 + ct*16 + l16;
        bf16x8 bfr = *(const bf16x8*)&Bs[n*64 + ((csel ^ (n & 7)))*8];
        acc[0][ct] = __builtin_amdgcn_mfma_f32_16x16x32_bf16(af[0], bfr, acc[0][ct], 0, 0, 0);
        acc[1][ct] = __builtin_amdgcn_mfma_f32_16x16x32_bf16(af[1], bfr, acc[1][ct], 0, 0, 0);
      }
    }
    __syncthreads();
  }
  // h2 -> LDS (bf16, swizzled for A-side reads)
#pragma unroll
  for (int rt = 0; rt < 2; ++rt)
#pragma unroll
    for (int q = 0; q < 4; ++q) {
      int lr = wrg*32 + rt*16 + lq*4 + q;
#pragma unroll
      for (int ct = 0; ct < 8; ++ct) {
        int n = wcg*128 + ct*16 + l16;
        h2s[lr*256 + (((n >> 3) ^ swz(lr))*8 + (n & 7))] =
            f2bf(tanh_fast(acc[rt][ct][q] + b2[n]));
      }
    }
  // stage W3p into Bs (64 x 256), swizzled
#pragma unroll
  for (int i = 0; i < 4; ++i) {
    int s = i*512 + tid;
    int r = s >> 5, cc = s & 31;
    *(uint4*)&Bs[r*256 + ((cc ^ swz(r)))*8] = *(const uint4*)&W3pB[r*256 + cc*8];
  }
  __syncthreads();
  // stage 2: each wave computes its own 16 rows x 64 params
  f32x4 pacc[4];
#pragma unroll
  for (int j = 0; j < 4; ++j) pacc[j] = (f32x4){0.f,0.f,0.f,0.f};
#pragma unroll
  for (int ks = 0; ks < 8; ++ks) {
    int chunk = ks*4 + lq;
    int ar = wv*16 + l16;
    bf16x8 af = *(const bf16x8*)&h2s[ar*256 + ((chunk ^ swz(ar)))*8];
#pragma unroll
    for (int ct = 0; ct < 4; ++ct) {
      int br = ct*16 + l16;
      bf16x8 bfr = *(const bf16x8*)&Bs[br*256 + ((chunk ^ swz(br)))*8];
      pacc[ct] = __builtin_amdgcn_mfma_f32_16x16x32_bf16(af, bfr, pacc[ct], 0, 0, 0);
    }
  }
  // params to own LDS region (reuse h2s rows of this wave), stride 68 fp32
  float* Ps = (float*)&h2s[wv*16*256];
#pragma unroll
  for (int ct = 0; ct < 4; ++ct) {
    int n = ct*16 + l16;
    float b = (n < 60) ? b3[n] : 0.0f;
#pragma unroll
    for (int q = 0; q < 4; ++q)
      Ps[(lq*4 + q)*68 + n] = pacc[ct][q] + b;
  }
  // per-row likelihood (wave-internal)
  if (lane < 16) {
    long grow = row0 + wv*16 + lane;
    float zv = z[grow];
    const float* p = &Ps[lane*68];
    float mx1 = -1e30f;
#pragma unroll
    for (int i = 0; i < NK; ++i) mx1 = fmaxf(mx1, p[i]);
    float s1 = 0.0f;
#pragma unroll
    for (int i = 0; i < NK; ++i) s1 += __expf(p[i] - mx1);
    float lse1 = mx1 + __logf(s1);
    float a[NK];
    float mx2 = -1e30f;
#pragma unroll
    for (int i = 0; i < NK; ++i) {
      float lg = p[i], me = p[20+i], ls = p[40+i];
      float e = __expf(-ls);
      float d = (zv - me) * e;
      float ai = -0.5f*d*d - ls - 0.5f*LOG2PI + lg;
      a[i] = ai;
      mx2 = fmaxf(mx2, ai);
    }
    float s2 = 0.0f;
#pragma unroll
    for (int i = 0; i < NK; ++i) s2 += __expf(a[i] - mx2);
    float lse2 = mx2 + __logf(s2);
    ll[grow] = lse2 - lse1;
  }
}

// out[b] = sum_{t < S_b} ll[b,t]
__global__ __launch_bounds__(256) void k_final(const float* __restrict__ bv,
    const float* __restrict__ mv, const float* __restrict__ ll,
    float* __restrict__ out) {
  int tid = threadIdx.x;
  int wave = tid >> 6, lane = tid & 63;
  int b = blockIdx.x*4 + wave;
  float q = mv[b*64 + lane] * (1.0f - bv[b*64 + lane]);
  unsigned long long bal = __ballot(q > 0.5f);
  int S = __popcll(bal);
  float val = (lane < S) ? ll[(long)b*64 + lane] : 0.0f;
#pragma unroll
  for (int off = 32; off > 0; off >>= 1) val += __shfl_down(val, off);
  if (lane == 0) out[b] = val;
}

extern "C" void kernel_launch(void* const* d_in, const int* in_sizes, int n_in,
                              void* d_out, int out_size, void* d_ws, size_t ws_size,
                              hipStream_t stream) {
  const float* z    = (const float*)d_in[0];
  const float* c    = (const float*)d_in[1];
  const float* bv   = (const float*)d_in[2];
  const float* mv   = (const float*)d_in[3];
  const float* W_ih = (const float*)d_in[4];
  const float* W_hh = (const float*)d_in[5];
  const float* b_ih = (const float*)d_in[6];
  const float* b_hh = (const float*)d_in[7];
  const float* W1   = (const float*)d_in[8];
  const float* b1   = (const float*)d_in[9];
  const float* W2   = (const float*)d_in[10];
  const float* b2   = (const float*)d_in[11];
  const float* W3   = (const float*)d_in[12];
  const float* b3   = (const float*)d_in[13];
  float* out = (float*)d_out;

  char* p = (char*)d_ws;
  auto alloc = [&](size_t bytes) {
    char* q = p;
    p += (bytes + 255) & ~(size_t)255;
    return q;
  };
  unsigned short* cbmB = (unsigned short*)alloc((size_t)BATCH*256*2);
  unsigned short* CW   = (unsigned short*)alloc((size_t)1024*256*2);
  unsigned short* WhhB = (unsigned short*)alloc((size_t)G3*256*2);
  unsigned short* W1aB = (unsigned short*)alloc((size_t)256*256*2);
  unsigned short* W2B  = (unsigned short*)alloc((size_t)256*256*2);
  unsigned short* W3pB = (unsigned short*)alloc((size_t)64*256*2);
  float* w0 = (float*)alloc((size_t)G3*4);
  float* gi = (float*)alloc((size_t)BATCH*G3*4);
  float* P1 = (float*)alloc((size_t)BATCH*256*4);
  float* ll = (float*)alloc((size_t)NROW*4);
  unsigned short* hs = (unsigned short*)alloc((size_t)NROW*HDIM*2);

  k_cvtall<<<6468, 256, 0, stream>>>(c, bv, mv, W_ih, W_hh, W1, W2, W3,
                                     cbmB, CW, WhhB, W1aB, W2B, W3pB, w0);
  k_pre<<<256, 512, 0, stream>>>(cbmB, CW, b_ih, b_hh, b1, gi, P1);
  k_gru<<<128, 1024, 0, stream>>>(z, gi, WhhB, b_hh, w0, hs);
  k_l1<<<NROW/128, 512, 0, stream>>>(hs, W1aB, P1, hs);
  k_l23<<<NROW/128, 512, 0, stream>>>(hs, W2B, b2, W3pB, b3, z, ll);
  k_final<<<BATCH/4, 256, 0, stream>>>(bv, mv, ll, out);
}

// Round 13
// 686.545 us; speedup vs baseline: 1.3953x; 1.3953x over previous
//
#include <hip/hip_runtime.h>
#include <hip/hip_bf16.h>

#define BATCH  4096
#define NCC    64
#define HDIM   256
#define G3     768
#define NROW   (BATCH*NCC)   // 262144
#define NK     20
#define LOG2PI 1.8378770664093453f

typedef __attribute__((ext_vector_type(8))) short bf16x8;
typedef __attribute__((ext_vector_type(4))) float f32x4;

__device__ __forceinline__ float sigm(float x) { return 1.0f/(1.0f + __expf(-x)); }
__device__ __forceinline__ float tanh_fast(float x) { return 1.0f - 2.0f/(__expf(2.0f*x) + 1.0f); }
__device__ __forceinline__ unsigned short f2bf(float x) {
  __hip_bfloat16 h = __float2bfloat16(x);
  return __builtin_bit_cast(unsigned short, h);
}
__device__ __forceinline__ int swz(int r) { return (r & 7) ^ ((r & 8) >> 2); }

// ---- one elementwise pass: build cbmB, CW, WhhB, W1aB, W2B, W3pB, w0 ----
__global__ __launch_bounds__(256) void k_cvtall(
    const float* __restrict__ c, const float* __restrict__ bv,
    const float* __restrict__ mv, const float* __restrict__ W_ih,
    const float* __restrict__ W_hh, const float* __restrict__ W1,
    const float* __restrict__ W2, const float* __restrict__ W3,
    unsigned short* __restrict__ cbmB, unsigned short* __restrict__ CW,
    unsigned short* __restrict__ WhhB, unsigned short* __restrict__ W1aB,
    unsigned short* __restrict__ W2B, unsigned short* __restrict__ W3pB,
    float* __restrict__ w0) {
  int idx = blockIdx.x*256 + threadIdx.x;
  if (idx < 1048576) {            // cbmB [4096][256], K-padded
    int row = idx >> 8, k = idx & 255;
    float v = 0.f;
    if (k < 80)       v = c [row*80 + k];
    else if (k < 144) v = bv[row*64 + (k-80)];
    else if (k < 208) v = mv[row*64 + (k-144)];
    cbmB[idx] = f2bf(v);
    return;
  }
  idx -= 1048576;
  if (idx < 262144) {             // CW [1024][256]: W_ih cols 1.. | W1 cols 256..
    int n = idx >> 8, k = idx & 255;
    float v = 0.f;
    if (n < 768) { if (k < 208) v = W_ih[n*209 + 1 + k]; }
    else         { if (k < 208) v = W1[(n-768)*464 + 256 + k]; }
    CW[idx] = f2bf(v);
    return;
  }
  idx -= 262144;
  if (idx < 196608) { WhhB[idx] = f2bf(W_hh[idx]); return; }
  idx -= 196608;
  if (idx < 65536) { int n = idx>>8, k = idx&255; W1aB[idx] = f2bf(W1[n*464+k]); return; }
  idx -= 65536;
  if (idx < 65536) { W2B[idx] = f2bf(W2[idx]); return; }
  idx -= 65536;
  if (idx < 16384) {
    int n = idx >> 8;
    float v = 0.f;
    if (n < 60) v = W3[idx];
    W3pB[idx] = f2bf(v);
    return;
  }
  idx -= 16384;
  if (idx < 768) w0[idx] = W_ih[idx*209];
}

// ---- pre-GEMM: [4096 x 1024 x 256(pad)] -> gi (+biases) / P1 (+b1) ----
__global__ __launch_bounds__(512) void k_pre(
    const unsigned short* __restrict__ A, const unsigned short* __restrict__ Bw,
    const float* __restrict__ b_ih, const float* __restrict__ b_hh,
    const float* __restrict__ b1,
    float* __restrict__ gi, float* __restrict__ P1) {
  __shared__ __align__(16) unsigned short As[128*64];
  __shared__ __align__(16) unsigned short Bs[128*64];
  int tid = threadIdx.x;
  int rb = blockIdx.x >> 3, cb = blockIdx.x & 7;
  long row0 = (long)rb * 128;
  int n0 = cb * 128;
  int wv = tid >> 6, lane = tid & 63;
  int lq = lane >> 4, l16 = lane & 15;
  int wrg = wv & 3, wcg = wv >> 2;
  f32x4 acc[2][4];
#pragma unroll
  for (int i = 0; i < 2; ++i)
#pragma unroll
    for (int j = 0; j < 4; ++j) acc[i][j] = (f32x4){0.f,0.f,0.f,0.f};
  for (int kb = 0; kb < 256; kb += 64) {
#pragma unroll
    for (int i = 0; i < 2; ++i) {
      int s = i*512 + tid;
      int r = s >> 3, cg = (s & 7) ^ (r & 7);
      *(uint4*)&As[s*8] = *(const uint4*)&A[(row0 + r)*256 + kb + cg*8];
      *(uint4*)&Bs[s*8] = *(const uint4*)&Bw[(long)(n0 + r)*256 + kb + cg*8];
    }
    __syncthreads();
#pragma unroll
    for (int kc = 0; kc < 2; ++kc) {
      int csel = kc*4 + lq;
      bf16x8 af[2];
#pragma unroll
      for (int rt = 0; rt < 2; ++rt) {
        int r = wrg*32 + rt*16 + l16;
        af[rt] = *(const bf16x8*)&As[r*64 + ((csel ^ (r & 7)))*8];
      }
#pragma unroll
      for (int ct = 0; ct < 4; ++ct) {
        int n = wcg*64 + ct*16 + l16;
        bf16x8 bfr = *(const bf16x8*)&Bs[n*64 + ((csel ^ (n & 7)))*8];
        acc[0][ct] = __builtin_amdgcn_mfma_f32_16x16x32_bf16(af[0], bfr, acc[0][ct], 0, 0, 0);
        acc[1][ct] = __builtin_amdgcn_mfma_f32_16x16x32_bf16(af[1], bfr, acc[1][ct], 0, 0, 0);
      }
    }
    __syncthreads();
  }
#pragma unroll
  for (int rt = 0; rt < 2; ++rt)
#pragma unroll
    for (int q = 0; q < 4; ++q) {
      long row = row0 + wrg*32 + rt*16 + lq*4 + q;
#pragma unroll
      for (int ct = 0; ct < 4; ++ct) {
        int n = n0 + wcg*64 + ct*16 + l16;
        float v = acc[rt][ct][q];
        if (n < 512)      gi[row*G3 + n] = v + b_ih[n] + b_hh[n];
        else if (n < 768) gi[row*G3 + n] = v + b_ih[n];
        else              P1[row*256 + (n-768)] = v + b1[n-768];
      }
    }
}

// ---- persistent GRU: 256 blocks x 16 rows, 512 threads (8 waves) ----
// wf[6][8] (192 regs) pinned into AGPRs via opaque inline asm: the asm def
// cannot be rematerialized (R9-R11: plain loads get remat'd into the t-loop,
// re-streaming 6.3 GB from L2 = the whole 267 us). MFMA reads B directly
// from AGPR (ISA 10). LDS 84 KB -> 1 block/CU -> 2 waves/SIMD -> the
// 192 AGPR + ~60 VGPR fit the 256-reg budget with zero occupancy cost.
__global__ __attribute__((amdgpu_flat_work_group_size(512, 512)))
__attribute__((amdgpu_waves_per_eu(2, 2)))
void k_gru(
    const float* __restrict__ z, const float* __restrict__ gi,
    const unsigned short* __restrict__ WhhB, const float* __restrict__ b_hh,
    const float* __restrict__ w0, unsigned short* __restrict__ hs) {
  __shared__ __align__(16) unsigned short hbf[2*16*256];  // two 8 KB buffers
  __shared__ __align__(16) float gis[768*20];             // gi^T, stride 20 fp32
  __shared__ __align__(16) float zs[64*16];               // z^T [t][row]
  __shared__ float wls[768 + 256];                        // w0 | b_hh n-gate
  int tid = threadIdx.x;
  int wv = tid >> 6, lane = tid & 63;
  int lq = lane >> 4, l16 = lane & 15;
  int row0 = blockIdx.x * 16;
  // Whh fragments: index [g*2+tt], col = g*256 + wv*32 + tt*16 + l16
  bf16x8 wf[6][8];
#pragma unroll
  for (int g = 0; g < 3; ++g)
#pragma unroll
    for (int tt = 0; tt < 2; ++tt)
#pragma unroll
      for (int ks = 0; ks < 8; ++ks)
        wf[g*2+tt][ks] = *(const bf16x8*)&WhhB[(long)(g*256 + wv*32 + tt*16 + l16)*256 + ks*32 + lq*8];
  // Pin into AGPRs. Opaque asm: no rematerialization possible; values must
  // stay resident in the AGPR file for the whole kernel.
#pragma unroll
  for (int f = 0; f < 6; ++f)
    __asm__ volatile("" : "+a"(wf[f][0]), "+a"(wf[f][1]), "+a"(wf[f][2]),
                          "+a"(wf[f][3]), "+a"(wf[f][4]), "+a"(wf[f][5]),
                          "+a"(wf[f][6]), "+a"(wf[f][7]));
  // stage w0 (768) and b_hh n-gate (256) into LDS
  for (int i = tid; i < 768; i += 512) wls[i] = w0[i];
  for (int i = tid; i < 256; i += 512) wls[768 + i] = b_hh[512 + i];
  // stage z (transposed) and gi slice (transposed, stride 20)
  for (int i = tid; i < 1024; i += 512) {
    int t = i >> 4, r = i & 15;
    zs[i] = z[(row0+r)*64 + t];
  }
#pragma unroll
  for (int i = 0; i < 24; ++i) {
    int s = i*512 + tid;               // 12288 elements
    int r = s / 768, cc = s - r*768;   // coalesced global read per row
    gis[cc*20 + r] = gi[(long)(row0+r)*768 + cc];
  }
  for (int i = tid; i < 2048; i += 512) ((unsigned int*)hbf)[i] = 0u;  // zero buf0
  float hp[2][4] = {{0.f,0.f,0.f,0.f},{0.f,0.f,0.f,0.f}};
  const int s7 = l16 & 7;
  const int arow = l16*256;
  const int r4 = lq*4;
  const int hc0 = wv*32 + l16;          // tt=0 col; tt=1 is +16
  // copy-out mapping: thread -> (row cr, chunk ccc)
  const int cr = tid >> 5, ccc = tid & 31;
  const int csrc = cr*256 + ((ccc ^ (cr & 7)))*8;
  unsigned short* cbase = hs + (long)(row0+cr)*64*256 + ccc*8;
  __syncthreads();
#pragma unroll 1
  for (int t = 0; t < 64; ++t) {
    const int co = (t & 1) << 12;      // current buffer offset (shorts)
    const int no = co ^ 4096;          // next buffer offset
    float zp[4];
    {
      float4 zv4 = *(const float4*)&zs[(t ? (t-1) : 0)*16 + r4];
#pragma unroll
      for (int q = 0; q < 4; ++q) zp[q] = t ? (&zv4.x)[q] : -1.0f;
    }
    // C-init: r,u gates from gi^T (b128 reads) + rank-1 z term; n-gate = b_hh_n
    f32x4 a[6];
#pragma unroll
    for (int tt = 0; tt < 2; ++tt) {
      int hc = hc0 + tt*16;
      f32x4 gR = *(const f32x4*)&gis[hc*20 + r4];
      f32x4 gU = *(const f32x4*)&gis[(256+hc)*20 + r4];
      float w0r = wls[hc], w0u = wls[256+hc], bn = wls[768 + hc];
#pragma unroll
      for (int q = 0; q < 4; ++q) {
        a[tt][q]   = gR[q] + zp[q]*w0r;
        a[2+tt][q] = gU[q] + zp[q]*w0u;
        a[4+tt][q] = bn;
      }
    }
#pragma unroll
    for (int ks = 0; ks < 8; ++ks) {
      bf16x8 af = *(const bf16x8*)&hbf[co + arow + (((ks*4+lq) ^ s7))*8];
#pragma unroll
      for (int f = 0; f < 6; ++f)
        a[f] = __builtin_amdgcn_mfma_f32_16x16x32_bf16(af, wf[f][ks], a[f], 0, 0, 0);
    }
    if (t) {                            // h_{t-1} copy-out (coalesced)
      uint4 cdat = *(const uint4*)&hbf[co + csrc];
      *(uint4*)(cbase + (t-1)*256) = cdat;
    }
    // epilogue: h_t = u*(h_{t-1}-n)+n, write to next buffer
#pragma unroll
    for (int tt = 0; tt < 2; ++tt) {
      int hc = hc0 + tt*16;
      int hchunk = hc >> 3, hlow = hc & 7;
      float w0n = wls[512 + hc];
      f32x4 gN = *(const f32x4*)&gis[(512+hc)*20 + r4];
#pragma unroll
      for (int q = 0; q < 4; ++q) {
        int r = r4 + q;
        float rr = sigm(a[tt][q]);
        float uu = sigm(a[2+tt][q]);
        float nn = tanh_fast(gN[q] + zp[q]*w0n + rr*a[4+tt][q]);
        float hn = uu*(hp[tt][q] - nn) + nn;
        hp[tt][q] = hn;
        hbf[no + r*256 + ((hchunk ^ (r & 7)))*8 + hlow] = f2bf(hn);
      }
    }
    __syncthreads();
  }
  // h_63 lives in buffer 0 (written by epilogue of t=63)
  uint4 cdat = *(const uint4*)&hbf[0 + csrc];
  *(uint4*)(cbase + 63*256) = cdat;
}

// ---- MLP layer 1, in-place: Out = tanh(A @ W1a^T + P1[row>>6]) ----
__global__ __launch_bounds__(512) void k_l1(
    const unsigned short* __restrict__ A, const unsigned short* __restrict__ Bw,
    const float* __restrict__ P1, unsigned short* __restrict__ Out) {
  __shared__ __align__(16) unsigned short As[128*64];
  __shared__ __align__(16) unsigned short Bs[256*64];
  int tid = threadIdx.x;
  long row0 = (long)blockIdx.x * 128;
  int wv = tid >> 6, lane = tid & 63;
  int lq = lane >> 4, l16 = lane & 15;
  int wrg = wv & 3, wcg = wv >> 2;
  f32x4 acc[2][8];
#pragma unroll
  for (int i = 0; i < 2; ++i)
#pragma unroll
    for (int j = 0; j < 8; ++j) acc[i][j] = (f32x4){0.f,0.f,0.f,0.f};
  for (int kb = 0; kb < 256; kb += 64) {
#pragma unroll
    for (int i = 0; i < 2; ++i) {
      int s = i*512 + tid;
      int r = s >> 3, cg = (s & 7) ^ (r & 7);
      *(uint4*)&As[s*8] = *(const uint4*)&A[(row0 + r)*256 + kb + cg*8];
    }
#pragma unroll
    for (int i = 0; i < 4; ++i) {
      int s = i*512 + tid;
      int r = s >> 3, cg = (s & 7) ^ (r & 7);
      *(uint4*)&Bs[s*8] = *(const uint4*)&Bw[(long)r*256 + kb + cg*8];
    }
    __syncthreads();
#pragma unroll
    for (int kc = 0; kc < 2; ++kc) {
      int csel = kc*4 + lq;
      bf16x8 af[2];
#pragma unroll
      for (int rt = 0; rt < 2; ++rt) {
        int r = wrg*32 + rt*16 + l16;
        af[rt] = *(const bf16x8*)&As[r*64 + ((csel ^ (r & 7)))*8];
      }
#pragma unroll
      for (int ct = 0; ct < 8; ++ct) {
        int n = wcg*128 + ct*16 + l16;
        bf16x8 bfr = *(const bf16x8*)&Bs[n*64 + ((csel ^ (n & 7)))*8];
        acc[0][ct] = __builtin_amdgcn_mfma_f32_16x16x32_bf16(af[0], bfr, acc[0][ct], 0, 0, 0);
        acc[1][ct] = __builtin_amdgcn_mfma_f32_16x16x32_bf16(af[1], bfr, acc[1][ct], 0, 0, 0);
      }
    }
    __syncthreads();
  }
#pragma unroll
  for (int rt = 0; rt < 2; ++rt)
#pragma unroll
    for (int q = 0; q < 4; ++q) {
      long row = row0 + wrg*32 + rt*16 + lq*4 + q;
#pragma unroll
      for (int ct = 0; ct < 8; ++ct) {
        int n = wcg*128 + ct*16 + l16;
        float b = P1[(row >> 6)*256 + n];
        Out[row*256 + n] = f2bf(tanh_fast(acc[rt][ct][q] + b));
      }
    }
}

// ---- fused MLP layer2 + layer3 + mixture likelihood ----
__global__ __launch_bounds__(512) void k_l23(
    const unsigned short* __restrict__ A, const unsigned short* __restrict__ W2B,
    const float* __restrict__ b2, const unsigned short* __restrict__ W3pB,
    const float* __restrict__ b3, const float* __restrict__ z,
    float* __restrict__ ll) {
  __shared__ __align__(16) unsigned short As[128*64];
  __shared__ __align__(16) unsigned short Bs[256*64];
  __shared__ __align__(16) unsigned short h2s[128*256];
  int tid = threadIdx.x;
  long row0 = (long)blockIdx.x * 128;
  int wv = tid >> 6, lane = tid & 63;
  int lq = lane >> 4, l16 = lane & 15;
  int wrg = wv & 3, wcg = wv >> 2;
  f32x4 acc[2][8];
#pragma unroll
  for (int i = 0; i < 2; ++i)
#pragma unroll
    for (int j = 0; j < 8; ++j) acc[i][j] = (f32x4){0.f,0.f,0.f,0.f};
  for (int kb = 0; kb < 256; kb += 64) {
#pragma unroll
    for (int i = 0; i < 2; ++i) {
      int s = i*512 + tid;
      int r = s >> 3, cg = (s & 7) ^ (r & 7);
      *(uint4*)&As[s*8] = *(const uint4*)&A[(row0 + r)*256 + kb + cg*8];
    }
#pragma unroll
    for (int i = 0; i < 4; ++i) {
      int s = i*512 + tid;
      int r = s >> 3, cg = (s & 7) ^ (r & 7);
      *(uint4*)&Bs[s*8] = *(const uint4*)&W2B[(long)r*256 + kb + cg*8];
    }
    __syncthreads();
#pragma unroll
    for (int kc = 0; kc < 2; ++kc) {
      int csel = kc*4 + lq;
      bf16x8 af[2];
#pragma unroll
      for (int rt = 0; rt < 2; ++rt) {
        int r = wrg*32 + rt*16 + l16;
        af[rt] = *(const bf16x8*)&As[r*64 + ((csel ^ (r & 7)))*8];
      }
#pragma unroll
      for (int ct = 0; ct < 8; ++ct) {
        int n = wcg*128 + ct*16 + l16;
        bf16x8 bfr = *(const bf16x8*)&Bs[n*64 + ((csel ^ (n & 7)))*8];
        acc[0][ct] = __builtin_amdgcn_mfma_f32_16x16x32_bf16(af[0], bfr, acc[0][ct], 0, 0, 0);
        acc[1][ct] = __builtin_amdgcn_mfma_f32_16x16x32_bf16(af[1], bfr, acc[1][ct], 0, 0, 0);
      }
    }
    __syncthreads();
  }
  // h2 -> LDS (bf16, swizzled for A-side reads)
#pragma unroll
  for (int rt = 0; rt < 2; ++rt)
#pragma unroll
    for (int q = 0; q < 4; ++q) {
      int lr = wrg*32 + rt*16 + lq*4 + q;
#pragma unroll
      for (int ct = 0; ct < 8; ++ct) {
        int n = wcg*128 + ct*16 + l16;
        h2s[lr*256 + (((n >> 3) ^ swz(lr))*8 + (n & 7))] =
            f2bf(tanh_fast(acc[rt][ct][q] + b2[n]));
      }
    }
  // stage W3p into Bs (64 x 256), swizzled
#pragma unroll
  for (int i = 0; i < 4; ++i) {
    int s = i*512 + tid;
    int r = s >> 5, cc = s & 31;
    *(uint4*)&Bs[r*256 + ((cc ^ swz(r)))*8] = *(const uint4*)&W3pB[r*256 + cc*8];
  }
  __syncthreads();
  // stage 2: each wave computes its own 16 rows x 64 params
  f32x4 pacc[4];
#pragma unroll
  for (int j = 0; j < 4; ++j) pacc[j] = (f32x4){0.f,0.f,0.f,0.f};
#pragma unroll
  for (int ks = 0; ks < 8; ++ks) {
    int chunk = ks*4 + lq;
    int ar = wv*16 + l16;
    bf16x8 af = *(const bf16x8*)&h2s[ar*256 + ((chunk ^ swz(ar)))*8];
#pragma unroll
    for (int ct = 0; ct < 4; ++ct) {
      int br = ct*16 + l16;
      bf16x8 bfr = *(const bf16x8*)&Bs[br*256 + ((chunk ^ swz(br)))*8];
      pacc[ct] = __builtin_amdgcn_mfma_f32_16x16x32_bf16(af, bfr, pacc[ct], 0, 0, 0);
    }
  }
  // params to own LDS region (reuse h2s rows of this wave), stride 68 fp32
  float* Ps = (float*)&h2s[wv*16*256];
#pragma unroll
  for (int ct = 0; ct < 4; ++ct) {
    int n = ct*16 + l16;
    float b = (n < 60) ? b3[n] : 0.0f;
#pragma unroll
    for (int q = 0; q < 4; ++q)
      Ps[(lq*4 + q)*68 + n] = pacc[ct][q] + b;
  }
  // per-row likelihood (wave-internal)
  if (lane < 16) {
    long grow = row0 + wv*16 + lane;
    float zv = z[grow];
    const float* p = &Ps[lane*68];
    float mx1 = -1e30f;
#pragma unroll
    for (int i = 0; i < NK; ++i) mx1 = fmaxf(mx1, p[i]);
    float s1 = 0.0f;
#pragma unroll
    for (int i = 0; i < NK; ++i) s1 += __expf(p[i] - mx1);
    float lse1 = mx1 + __logf(s1);
    float a[NK];
    float mx2 = -1e30f;
#pragma unroll
    for (int i = 0; i < NK; ++i) {
      float lg = p[i], me = p[20+i], ls = p[40+i];
      float e = __expf(-ls);
      float d = (zv - me) * e;
      float ai = -0.5f*d*d - ls - 0.5f*LOG2PI + lg;
      a[i] = ai;
      mx2 = fmaxf(mx2, ai);
    }
    float s2 = 0.0f;
#pragma unroll
    for (int i = 0; i < NK; ++i) s2 += __expf(a[i] - mx2);
    float lse2 = mx2 + __logf(s2);
    ll[grow] = lse2 - lse1;
  }
}

// out[b] = sum_{t < S_b} ll[b,t]
__global__ __launch_bounds__(256) void k_final(const float* __restrict__ bv,
    const float* __restrict__ mv, const float* __restrict__ ll,
    float* __restrict__ out) {
  int tid = threadIdx.x;
  int wave = tid >> 6, lane = tid & 63;
  int b = blockIdx.x*4 + wave;
  float q = mv[b*64 + lane] * (1.0f - bv[b*64 + lane]);
  unsigned long long bal = __ballot(q > 0.5f);
  int S = __popcll(bal);
  float val = (lane < S) ? ll[(long)b*64 + lane] : 0.0f;
#pragma unroll
  for (int off = 32; off > 0; off >>= 1) val += __shfl_down(val, off);
  if (lane == 0) out[b] = val;
}

extern "C" void kernel_launch(void* const* d_in, const int* in_sizes, int n_in,
                              void* d_out, int out_size, void* d_ws, size_t ws_size,
                              hipStream_t stream) {
  const float* z    = (const float*)d_in[0];
  const float* c    = (const float*)d_in[1];
  const float* bv   = (const float*)d_in[2];
  const float* mv   = (const float*)d_in[3];
  const float* W_ih = (const float*)d_in[4];
  const float* W_hh = (const float*)d_in[5];
  const float* b_ih = (const float*)d_in[6];
  const float* b_hh = (const float*)d_in[7];
  const float* W1   = (const float*)d_in[8];
  const float* b1   = (const float*)d_in[9];
  const float* W2   = (const float*)d_in[10];
  const float* b2   = (const float*)d_in[11];
  const float* W3   = (const float*)d_in[12];
  const float* b3   = (const float*)d_in[13];
  float* out = (float*)d_out;

  char* p = (char*)d_ws;
  auto alloc = [&](size_t bytes) {
    char* q = p;
    p += (bytes + 255) & ~(size_t)255;
    return q;
  };
  unsigned short* cbmB = (unsigned short*)alloc((size_t)BATCH*256*2);
  unsigned short* CW   = (unsigned short*)alloc((size_t)1024*256*2);
  unsigned short* WhhB = (unsigned short*)alloc((size_t)G3*256*2);
  unsigned short* W1aB = (unsigned short*)alloc((size_t)256*256*2);
  unsigned short* W2B  = (unsigned short*)alloc((size_t)256*256*2);
  unsigned short* W3pB = (unsigned short*)alloc((size_t)64*256*2);
  float* w0 = (float*)alloc((size_t)G3*4);
  float* gi = (float*)alloc((size_t)BATCH*G3*4);
  float* P1 = (float*)alloc((size_t)BATCH*256*4);
  float* ll = (float*)alloc((size_t)NROW*4);
  unsigned short* hs = (unsigned short*)alloc((size_t)NROW*HDIM*2);

  k_cvtall<<<6468, 256, 0, stream>>>(c, bv, mv, W_ih, W_hh, W1, W2, W3,
                                     cbmB, CW, WhhB, W1aB, W2B, W3pB, w0);
  k_pre<<<256, 512, 0, stream>>>(cbmB, CW, b_ih, b_hh, b1, gi, P1);
  k_gru<<<256, 512, 0, stream>>>(z, gi, WhhB, b_hh, w0, hs);
  k_l1<<<NROW/128, 512, 0, stream>>>(hs, W1aB, P1, hs);
  k_l23<<<NROW/128, 512, 0, stream>>>(hs, W2B, b2, W3pB, b3, z, ll);
  k_final<<<BATCH/4, 256, 0, stream>>>(bv, mv, ll, out);
}

// Round 14
// 558.153 us; speedup vs baseline: 1.7163x; 1.2300x over previous
//
#include <hip/hip_runtime.h>
#include <hip/hip_bf16.h>

#define BATCH  4096
#define NCC    64
#define HDIM   256
#define G3     768
#define NROW   (BATCH*NCC)   // 262144
#define NK     20
#define LOG2PI 1.8378770664093453f

typedef __attribute__((ext_vector_type(8))) short bf16x8;
typedef __attribute__((ext_vector_type(4))) float f32x4;

__device__ __forceinline__ float sigm(float x) { return 1.0f/(1.0f + __expf(-x)); }
__device__ __forceinline__ float tanh_fast(float x) { return 1.0f - 2.0f/(__expf(2.0f*x) + 1.0f); }
__device__ __forceinline__ unsigned short f2bf(float x) {
  __hip_bfloat16 h = __float2bfloat16(x);
  return __builtin_bit_cast(unsigned short, h);
}
__device__ __forceinline__ int swz(int r) { return (r & 7) ^ ((r & 8) >> 2); }

// ---- one elementwise pass: build cbmB, CW, WhhB, W1aB, W2B, W3pB, w0 ----
__global__ __launch_bounds__(256) void k_cvtall(
    const float* __restrict__ c, const float* __restrict__ bv,
    const float* __restrict__ mv, const float* __restrict__ W_ih,
    const float* __restrict__ W_hh, const float* __restrict__ W1,
    const float* __restrict__ W2, const float* __restrict__ W3,
    unsigned short* __restrict__ cbmB, unsigned short* __restrict__ CW,
    unsigned short* __restrict__ WhhB, unsigned short* __restrict__ W1aB,
    unsigned short* __restrict__ W2B, unsigned short* __restrict__ W3pB,
    float* __restrict__ w0) {
  int idx = blockIdx.x*256 + threadIdx.x;
  if (idx < 1048576) {            // cbmB [4096][256], K-padded
    int row = idx >> 8, k = idx & 255;
    float v = 0.f;
    if (k < 80)       v = c [row*80 + k];
    else if (k < 144) v = bv[row*64 + (k-80)];
    else if (k < 208) v = mv[row*64 + (k-144)];
    cbmB[idx] = f2bf(v);
    return;
  }
  idx -= 1048576;
  if (idx < 262144) {             // CW [1024][256]: W_ih cols 1.. | W1 cols 256..
    int n = idx >> 8, k = idx & 255;
    float v = 0.f;
    if (n < 768) { if (k < 208) v = W_ih[n*209 + 1 + k]; }
    else         { if (k < 208) v = W1[(n-768)*464 + 256 + k]; }
    CW[idx] = f2bf(v);
    return;
  }
  idx -= 262144;
  if (idx < 196608) { WhhB[idx] = f2bf(W_hh[idx]); return; }
  idx -= 196608;
  if (idx < 65536) { int n = idx>>8, k = idx&255; W1aB[idx] = f2bf(W1[n*464+k]); return; }
  idx -= 65536;
  if (idx < 65536) { W2B[idx] = f2bf(W2[idx]); return; }
  idx -= 65536;
  if (idx < 16384) {
    int n = idx >> 8;
    float v = 0.f;
    if (n < 60) v = W3[idx];
    W3pB[idx] = f2bf(v);
    return;
  }
  idx -= 16384;
  if (idx < 768) w0[idx] = W_ih[idx*209];
}

// ---- pre-GEMM: [4096 x 1024 x 256(pad)] -> gi (+biases) / P1 (+b1) ----
__global__ __launch_bounds__(512) void k_pre(
    const unsigned short* __restrict__ A, const unsigned short* __restrict__ Bw,
    const float* __restrict__ b_ih, const float* __restrict__ b_hh,
    const float* __restrict__ b1,
    float* __restrict__ gi, float* __restrict__ P1) {
  __shared__ __align__(16) unsigned short As[128*64];
  __shared__ __align__(16) unsigned short Bs[128*64];
  int tid = threadIdx.x;
  int rb = blockIdx.x >> 3, cb = blockIdx.x & 7;
  long row0 = (long)rb * 128;
  int n0 = cb * 128;
  int wv = tid >> 6, lane = tid & 63;
  int lq = lane >> 4, l16 = lane & 15;
  int wrg = wv & 3, wcg = wv >> 2;
  f32x4 acc[2][4];
#pragma unroll
  for (int i = 0; i < 2; ++i)
#pragma unroll
    for (int j = 0; j < 4; ++j) acc[i][j] = (f32x4){0.f,0.f,0.f,0.f};
  for (int kb = 0; kb < 256; kb += 64) {
#pragma unroll
    for (int i = 0; i < 2; ++i) {
      int s = i*512 + tid;
      int r = s >> 3, cg = (s & 7) ^ (r & 7);
      *(uint4*)&As[s*8] = *(const uint4*)&A[(row0 + r)*256 + kb + cg*8];
      *(uint4*)&Bs[s*8] = *(const uint4*)&Bw[(long)(n0 + r)*256 + kb + cg*8];
    }
    __syncthreads();
#pragma unroll
    for (int kc = 0; kc < 2; ++kc) {
      int csel = kc*4 + lq;
      bf16x8 af[2];
#pragma unroll
      for (int rt = 0; rt < 2; ++rt) {
        int r = wrg*32 + rt*16 + l16;
        af[rt] = *(const bf16x8*)&As[r*64 + ((csel ^ (r & 7)))*8];
      }
#pragma unroll
      for (int ct = 0; ct < 4; ++ct) {
        int n = wcg*64 + ct*16 + l16;
        bf16x8 bfr = *(const bf16x8*)&Bs[n*64 + ((csel ^ (n & 7)))*8];
        acc[0][ct] = __builtin_amdgcn_mfma_f32_16x16x32_bf16(af[0], bfr, acc[0][ct], 0, 0, 0);
        acc[1][ct] = __builtin_amdgcn_mfma_f32_16x16x32_bf16(af[1], bfr, acc[1][ct], 0, 0, 0);
      }
    }
    __syncthreads();
  }
#pragma unroll
  for (int rt = 0; rt < 2; ++rt)
#pragma unroll
    for (int q = 0; q < 4; ++q) {
      long row = row0 + wrg*32 + rt*16 + lq*4 + q;
#pragma unroll
      for (int ct = 0; ct < 4; ++ct) {
        int n = n0 + wcg*64 + ct*16 + l16;
        float v = acc[rt][ct][q];
        if (n < 512)      gi[row*G3 + n] = v + b_ih[n] + b_hh[n];
        else if (n < 768) gi[row*G3 + n] = v + b_ih[n];
        else              P1[row*256 + (n-768)] = v + b1[n-768];
      }
    }
}

// ---- persistent GRU (R9 proven form, 267 us): 256 blocks x 16 rows, 512 thr.
// Whh streams from L2 each step (compiler remats the loads; all residency
// attempts R7-R13 failed). ~70% of the per-XCD L2-BW bound. ----
__global__ __attribute__((amdgpu_flat_work_group_size(512, 512)))
__attribute__((amdgpu_waves_per_eu(2, 2)))
void k_gru(
    const float* __restrict__ z, const float* __restrict__ gi,
    const unsigned short* __restrict__ WhhB, const float* __restrict__ b_hh,
    const float* __restrict__ w0, unsigned short* __restrict__ hs) {
  __shared__ __align__(16) unsigned short hbf[2*16*256];  // two 8 KB buffers
  __shared__ __align__(16) float gis[768*20];             // gi^T, stride 20 fp32
  __shared__ __align__(16) float zs[64*16];               // z^T [t][row]
  __shared__ float wls[768 + 256];                        // w0 | b_hh n-gate
  int tid = threadIdx.x;
  int wv = tid >> 6, lane = tid & 63;
  int lq = lane >> 4, l16 = lane & 15;
  int row0 = blockIdx.x * 16;
  bf16x8 wf[6][8];
#pragma unroll
  for (int g = 0; g < 3; ++g)
#pragma unroll
    for (int tt = 0; tt < 2; ++tt)
#pragma unroll
      for (int ks = 0; ks < 8; ++ks)
        wf[g*2+tt][ks] = *(const bf16x8*)&WhhB[(long)(g*256 + wv*32 + tt*16 + l16)*256 + ks*32 + lq*8];
  for (int i = tid; i < 768; i += 512) wls[i] = w0[i];
  for (int i = tid; i < 256; i += 512) wls[768 + i] = b_hh[512 + i];
  for (int i = tid; i < 1024; i += 512) {
    int t = i >> 4, r = i & 15;
    zs[i] = z[(row0+r)*64 + t];
  }
#pragma unroll
  for (int i = 0; i < 24; ++i) {
    int s = i*512 + tid;
    int r = s / 768, cc = s - r*768;
    gis[cc*20 + r] = gi[(long)(row0+r)*768 + cc];
  }
  for (int i = tid; i < 2048; i += 512) ((unsigned int*)hbf)[i] = 0u;
  float hp[2][4] = {{0.f,0.f,0.f,0.f},{0.f,0.f,0.f,0.f}};
  const int s7 = l16 & 7;
  const int arow = l16*256;
  const int r4 = lq*4;
  const int hc0 = wv*32 + l16;
  const int cr = tid >> 5, ccc = tid & 31;
  const int csrc = cr*256 + ((ccc ^ (cr & 7)))*8;
  unsigned short* cbase = hs + (long)(row0+cr)*64*256 + ccc*8;
  __syncthreads();
#pragma unroll 1
  for (int t = 0; t < 64; ++t) {
    const int co = (t & 1) << 12;
    const int no = co ^ 4096;
    float zp[4];
    {
      float4 zv4 = *(const float4*)&zs[(t ? (t-1) : 0)*16 + r4];
#pragma unroll
      for (int q = 0; q < 4; ++q) zp[q] = t ? (&zv4.x)[q] : -1.0f;
    }
    f32x4 a[6];
#pragma unroll
    for (int tt = 0; tt < 2; ++tt) {
      int hc = hc0 + tt*16;
      f32x4 gR = *(const f32x4*)&gis[hc*20 + r4];
      f32x4 gU = *(const f32x4*)&gis[(256+hc)*20 + r4];
      float w0r = wls[hc], w0u = wls[256+hc], bn = wls[768 + hc];
#pragma unroll
      for (int q = 0; q < 4; ++q) {
        a[tt][q]   = gR[q] + zp[q]*w0r;
        a[2+tt][q] = gU[q] + zp[q]*w0u;
        a[4+tt][q] = bn;
      }
    }
#pragma unroll
    for (int ks = 0; ks < 8; ++ks) {
      bf16x8 af = *(const bf16x8*)&hbf[co + arow + (((ks*4+lq) ^ s7))*8];
#pragma unroll
      for (int f = 0; f < 6; ++f)
        a[f] = __builtin_amdgcn_mfma_f32_16x16x32_bf16(af, wf[f][ks], a[f], 0, 0, 0);
    }
    if (t) {
      uint4 cdat = *(const uint4*)&hbf[co + csrc];
      *(uint4*)(cbase + (t-1)*256) = cdat;
    }
#pragma unroll
    for (int tt = 0; tt < 2; ++tt) {
      int hc = hc0 + tt*16;
      int hchunk = hc >> 3, hlow = hc & 7;
      float w0n = wls[512 + hc];
      f32x4 gN = *(const f32x4*)&gis[(512+hc)*20 + r4];
#pragma unroll
      for (int q = 0; q < 4; ++q) {
        int r = r4 + q;
        float rr = sigm(a[tt][q]);
        float uu = sigm(a[2+tt][q]);
        float nn = tanh_fast(gN[q] + zp[q]*w0n + rr*a[4+tt][q]);
        float hn = uu*(hp[tt][q] - nn) + nn;
        hp[tt][q] = hn;
        hbf[no + r*256 + ((hchunk ^ (r & 7)))*8 + hlow] = f2bf(hn);
      }
    }
    __syncthreads();
  }
  uint4 cdat = *(const uint4*)&hbf[0 + csrc];
  *(uint4*)(cbase + 63*256) = cdat;
}

// ---- fused MLP: l1 + l2 + l3 + likelihood, one pass over hs ----
// 64 rows/block (one batch row), 512 threads, LDS 72 KB -> 2 blocks/CU.
// Overlays (barrier-separated): h1s region <- h2 <- Ps. Saves the 268 MB
// h1 HBM round-trip that the split k_l1/k_l23 paid.
__global__ __launch_bounds__(512) void k_mlp(
    const unsigned short* __restrict__ hs, const unsigned short* __restrict__ W1aB,
    const float* __restrict__ P1, const unsigned short* __restrict__ W2B,
    const float* __restrict__ b2, const unsigned short* __restrict__ W3pB,
    const float* __restrict__ b3, const float* __restrict__ z,
    float* __restrict__ ll) {
  __shared__ __align__(16) unsigned short As[64*64];     // 8 KB  (hs K-slab)
  __shared__ __align__(16) unsigned short Bs[256*64];    // 32 KB (weight slab / W3)
  __shared__ __align__(16) unsigned short h1s[64*256];   // 32 KB (h1 -> h2 -> Ps)
  int tid = threadIdx.x;
  int blk = blockIdx.x;
  long row0 = (long)blk * 64;
  int wv = tid >> 6, lane = tid & 63;
  int lq = lane >> 4, l16 = lane & 15;
  int wrg = wv & 3, wcg = wv >> 2;      // 4 row-tiles x 2 col-halves
  // ---------- layer 1: h1 = tanh(hs @ W1a^T + P1[blk]) ----------
  {
    f32x4 acc[8];
#pragma unroll
    for (int j = 0; j < 8; ++j) acc[j] = (f32x4){0.f,0.f,0.f,0.f};
    for (int kb = 0; kb < 256; kb += 64) {
      {
        int s = tid;
        int r = s >> 3, cg = (s & 7) ^ (r & 7);
        *(uint4*)&As[s*8] = *(const uint4*)&hs[(row0 + r)*256 + kb + cg*8];
      }
#pragma unroll
      for (int i = 0; i < 4; ++i) {
        int s = i*512 + tid;
        int r = s >> 3, cg = (s & 7) ^ (r & 7);
        *(uint4*)&Bs[s*8] = *(const uint4*)&W1aB[(long)r*256 + kb + cg*8];
      }
      __syncthreads();
#pragma unroll
      for (int kc = 0; kc < 2; ++kc) {
        int csel = kc*4 + lq;
        int ar = wrg*16 + l16;
        bf16x8 af = *(const bf16x8*)&As[ar*64 + ((csel ^ (ar & 7)))*8];
#pragma unroll
        for (int ct = 0; ct < 8; ++ct) {
          int n = wcg*128 + ct*16 + l16;
          bf16x8 bfr = *(const bf16x8*)&Bs[n*64 + ((csel ^ (n & 7)))*8];
          acc[ct] = __builtin_amdgcn_mfma_f32_16x16x32_bf16(af, bfr, acc[ct], 0, 0, 0);
        }
      }
      __syncthreads();
    }
#pragma unroll
    for (int q = 0; q < 4; ++q) {
      int rl = wrg*16 + lq*4 + q;
#pragma unroll
      for (int ct = 0; ct < 8; ++ct) {
        int n = wcg*128 + ct*16 + l16;
        float v = tanh_fast(acc[ct][q] + P1[blk*256 + n]);
        h1s[rl*256 + (((n>>3) ^ swz(rl))*8 + (n&7))] = f2bf(v);
      }
    }
  }
  __syncthreads();   // publish h1s
  // ---------- layer 2: h2 = tanh(h1 @ W2^T + b2) ----------
  {
    f32x4 acc[8];
#pragma unroll
    for (int j = 0; j < 8; ++j) acc[j] = (f32x4){0.f,0.f,0.f,0.f};
    for (int kb4 = 0; kb4 < 4; ++kb4) {
#pragma unroll
      for (int i = 0; i < 4; ++i) {
        int s = i*512 + tid;
        int r = s >> 3, cg = (s & 7) ^ (r & 7);
        *(uint4*)&Bs[s*8] = *(const uint4*)&W2B[(long)r*256 + kb4*64 + cg*8];
      }
      __syncthreads();
#pragma unroll
      for (int kc = 0; kc < 2; ++kc) {
        int csel = kc*4 + lq;
        int cglob = kb4*8 + csel;
        int ar = wrg*16 + l16;
        bf16x8 af = *(const bf16x8*)&h1s[ar*256 + ((cglob ^ swz(ar)))*8];
#pragma unroll
        for (int ct = 0; ct < 8; ++ct) {
          int n = wcg*128 + ct*16 + l16;
          bf16x8 bfr = *(const bf16x8*)&Bs[n*64 + ((csel ^ (n & 7)))*8];
          acc[ct] = __builtin_amdgcn_mfma_f32_16x16x32_bf16(af, bfr, acc[ct], 0, 0, 0);
        }
      }
      __syncthreads();
    }
    // all h1 reads done (barrier above) -> overwrite h1s with h2 (same swizzle)
#pragma unroll
    for (int q = 0; q < 4; ++q) {
      int rl = wrg*16 + lq*4 + q;
#pragma unroll
      for (int ct = 0; ct < 8; ++ct) {
        int n = wcg*128 + ct*16 + l16;
        float v = tanh_fast(acc[ct][q] + b2[n]);
        h1s[rl*256 + (((n>>3) ^ swz(rl))*8 + (n&7))] = f2bf(v);
      }
    }
  }
  // stage W3p into Bs (64 rows x 256 K, chunk-swizzled)
#pragma unroll
  for (int i = 0; i < 2; ++i) {
    int s = i*512 + tid;
    int r = s >> 4, cc = s & 15;       // 1024 uint4: 64 rows x 16? no: 64x32
    (void)r; (void)cc;
  }
#pragma unroll
  for (int i = 0; i < 4; ++i) {
    int s = i*512 + tid;               // 2048 slots of 8B -> use 8B stores
    int r = s >> 5, cc = s & 31;
    if (s < 2048) {
      *(uint2*)&Bs[r*256 + ((cc ^ swz(r)))*8 + (0)] =
          *(const uint2*)&W3pB[r*256 + cc*8];
      // upper half of the 16B chunk
    }
  }
  // NOTE: the above wrote only 8 of each 16B chunk; fix with second pass
#pragma unroll
  for (int i = 0; i < 4; ++i) {
    int s = i*512 + tid;
    int r = s >> 5, cc = s & 31;
    if (s < 2048) {
      *(uint2*)&Bs[r*256 + ((cc ^ swz(r)))*8 + 4] =
          *(const uint2*)&W3pB[r*256 + cc*8 + 4];
    }
  }
  __syncthreads();   // publish h2 (in h1s) and W3p (in Bs)
  // ---------- layer 3: params = h2 @ W3p^T + b3 ----------
  {
    int mt = wv & 3, np = wv >> 2;
    f32x4 pacc[2];
#pragma unroll
    for (int j = 0; j < 2; ++j) pacc[j] = (f32x4){0.f,0.f,0.f,0.f};
#pragma unroll
    for (int ks = 0; ks < 8; ++ks) {
      int chunk = ks*4 + lq;
      int ar = mt*16 + l16;
      bf16x8 af = *(const bf16x8*)&h1s[ar*256 + ((chunk ^ swz(ar)))*8];
#pragma unroll
      for (int j = 0; j < 2; ++j) {
        int br = (np*2 + j)*16 + l16;
        bf16x8 bfr = *(const bf16x8*)&Bs[br*256 + ((chunk ^ swz(br)))*8];
        pacc[j] = __builtin_amdgcn_mfma_f32_16x16x32_bf16(af, bfr, pacc[j], 0, 0, 0);
      }
    }
    __syncthreads();  // all h2 reads done -> Ps may overlay h1s
    float* Ps = (float*)h1s;           // 64 x 68 fp32 = 17.4 KB
#pragma unroll
    for (int j = 0; j < 2; ++j) {
      int n = (np*2 + j)*16 + l16;
      float b = (n < 60) ? b3[n] : 0.0f;
#pragma unroll
      for (int q = 0; q < 4; ++q)
        Ps[(mt*16 + lq*4 + q)*68 + n] = pacc[j][q] + b;
    }
  }
  __syncthreads();
  // ---------- likelihood ----------
  if (wv < 4 && lane < 16) {
    const float* Ps = (const float*)h1s;
    int rl = wv*16 + lane;
    long grow = row0 + rl;
    float zv = z[grow];
    const float* p = &Ps[rl*68];
    float mx1 = -1e30f;
#pragma unroll
    for (int i = 0; i < NK; ++i) mx1 = fmaxf(mx1, p[i]);
    float s1 = 0.0f;
#pragma unroll
    for (int i = 0; i < NK; ++i) s1 += __expf(p[i] - mx1);
    float lse1 = mx1 + __logf(s1);
    float a[NK];
    float mx2 = -1e30f;
#pragma unroll
    for (int i = 0; i < NK; ++i) {
      float lg = p[i], me = p[20+i], ls = p[40+i];
      float e = __expf(-ls);
      float d = (zv - me) * e;
      float ai = -0.5f*d*d - ls - 0.5f*LOG2PI + lg;
      a[i] = ai;
      mx2 = fmaxf(mx2, ai);
    }
    float s2 = 0.0f;
#pragma unroll
    for (int i = 0; i < NK; ++i) s2 += __expf(a[i] - mx2);
    float lse2 = mx2 + __logf(s2);
    ll[grow] = lse2 - lse1;
  }
}

// out[b] = sum_{t < S_b} ll[b,t]
__global__ __launch_bounds__(256) void k_final(const float* __restrict__ bv,
    const float* __restrict__ mv, const float* __restrict__ ll,
    float* __restrict__ out) {
  int tid = threadIdx.x;
  int wave = tid >> 6, lane = tid & 63;
  int b = blockIdx.x*4 + wave;
  float q = mv[b*64 + lane] * (1.0f - bv[b*64 + lane]);
  unsigned long long bal = __ballot(q > 0.5f);
  int S = __popcll(bal);
  float val = (lane < S) ? ll[(long)b*64 + lane] : 0.0f;
#pragma unroll
  for (int off = 32; off > 0; off >>= 1) val += __shfl_down(val, off);
  if (lane == 0) out[b] = val;
}

extern "C" void kernel_launch(void* const* d_in, const int* in_sizes, int n_in,
                              void* d_out, int out_size, void* d_ws, size_t ws_size,
                              hipStream_t stream) {
  const float* z    = (const float*)d_in[0];
  const float* c    = (const float*)d_in[1];
  const float* bv   = (const float*)d_in[2];
  const float* mv   = (const float*)d_in[3];
  const float* W_ih = (const float*)d_in[4];
  const float* W_hh = (const float*)d_in[5];
  const float* b_ih = (const float*)d_in[6];
  const float* b_hh = (const float*)d_in[7];
  const float* W1   = (const float*)d_in[8];
  const float* b1   = (const float*)d_in[9];
  const float* W2   = (const float*)d_in[10];
  const float* b2   = (const float*)d_in[11];
  const float* W3   = (const float*)d_in[12];
  const float* b3   = (const float*)d_in[13];
  float* out = (float*)d_out;

  char* p = (char*)d_ws;
  auto alloc = [&](size_t bytes) {
    char* q = p;
    p += (bytes + 255) & ~(size_t)255;
    return q;
  };
  unsigned short* cbmB = (unsigned short*)alloc((size_t)BATCH*256*2);
  unsigned short* CW   = (unsigned short*)alloc((size_t)1024*256*2);
  unsigned short* WhhB = (unsigned short*)alloc((size_t)G3*256*2);
  unsigned short* W1aB = (unsigned short*)alloc((size_t)256*256*2);
  unsigned short* W2B  = (unsigned short*)alloc((size_t)256*256*2);
  unsigned short* W3pB = (unsigned short*)alloc((size_t)64*256*2);
  float* w0 = (float*)alloc((size_t)G3*4);
  float* gi = (float*)alloc((size_t)BATCH*G3*4);
  float* P1 = (float*)alloc((size_t)BATCH*256*4);
  float* ll = (float*)alloc((size_t)NROW*4);
  unsigned short* hs = (unsigned short*)alloc((size_t)NROW*HDIM*2);

  k_cvtall<<<6468, 256, 0, stream>>>(c, bv, mv, W_ih, W_hh, W1, W2, W3,
                                     cbmB, CW, WhhB, W1aB, W2B, W3pB, w0);
  k_pre<<<256, 512, 0, stream>>>(cbmB, CW, b_ih, b_hh, b1, gi, P1);
  k_gru<<<256, 512, 0, stream>>>(z, gi, WhhB, b_hh, w0, hs);
  k_mlp<<<BATCH, 512, 0, stream>>>(hs, W1aB, P1, W2B, b2, W3pB, b3, z, ll);
  k_final<<<BATCH/4, 256, 0, stream>>>(bv, mv, ll, out);
}

// Round 15
// 517.119 us; speedup vs baseline: 1.8524x; 1.0794x over previous
//
#include <hip/hip_runtime.h>
#include <hip/hip_bf16.h>

#define BATCH  4096
#define NCC    64
#define HDIM   256
#define G3     768
#define NROW   (BATCH*NCC)   // 262144
#define NK     20
#define LOG2PI 1.8378770664093453f

typedef __attribute__((ext_vector_type(8))) short bf16x8;
typedef __attribute__((ext_vector_type(4))) float f32x4;

__device__ __forceinline__ float sigm(float x) { return 1.0f/(1.0f + __expf(-x)); }
__device__ __forceinline__ float tanh_fast(float x) { return 1.0f - 2.0f/(__expf(2.0f*x) + 1.0f); }
__device__ __forceinline__ unsigned short f2bf(float x) {
  __hip_bfloat16 h = __float2bfloat16(x);
  return __builtin_bit_cast(unsigned short, h);
}
__device__ __forceinline__ int swz(int r) { return (r & 7) ^ ((r & 8) >> 2); }

// ---- one elementwise pass: build cbmB, CW, WhhB, W1aB, W2B, W3pB, w0 ----
__global__ __launch_bounds__(256) void k_cvtall(
    const float* __restrict__ c, const float* __restrict__ bv,
    const float* __restrict__ mv, const float* __restrict__ W_ih,
    const float* __restrict__ W_hh, const float* __restrict__ W1,
    const float* __restrict__ W2, const float* __restrict__ W3,
    unsigned short* __restrict__ cbmB, unsigned short* __restrict__ CW,
    unsigned short* __restrict__ WhhB, unsigned short* __restrict__ W1aB,
    unsigned short* __restrict__ W2B, unsigned short* __restrict__ W3pB,
    float* __restrict__ w0) {
  int idx = blockIdx.x*256 + threadIdx.x;
  if (idx < 1048576) {            // cbmB [4096][256], K-padded
    int row = idx >> 8, k = idx & 255;
    float v = 0.f;
    if (k < 80)       v = c [row*80 + k];
    else if (k < 144) v = bv[row*64 + (k-80)];
    else if (k < 208) v = mv[row*64 + (k-144)];
    cbmB[idx] = f2bf(v);
    return;
  }
  idx -= 1048576;
  if (idx < 262144) {             // CW [1024][256]: W_ih cols 1.. | W1 cols 256..
    int n = idx >> 8, k = idx & 255;
    float v = 0.f;
    if (n < 768) { if (k < 208) v = W_ih[n*209 + 1 + k]; }
    else         { if (k < 208) v = W1[(n-768)*464 + 256 + k]; }
    CW[idx] = f2bf(v);
    return;
  }
  idx -= 262144;
  if (idx < 196608) { WhhB[idx] = f2bf(W_hh[idx]); return; }
  idx -= 196608;
  if (idx < 65536) { int n = idx>>8, k = idx&255; W1aB[idx] = f2bf(W1[n*464+k]); return; }
  idx -= 65536;
  if (idx < 65536) { W2B[idx] = f2bf(W2[idx]); return; }
  idx -= 65536;
  if (idx < 16384) {
    int n = idx >> 8;
    float v = 0.f;
    if (n < 60) v = W3[idx];
    W3pB[idx] = f2bf(v);
    return;
  }
  idx -= 16384;
  if (idx < 768) w0[idx] = W_ih[idx*209];
}

// ---- pre-GEMM: [4096 x 1024 x 256(pad)] -> gi (+biases) / P1 (+b1) ----
__global__ __launch_bounds__(512) void k_pre(
    const unsigned short* __restrict__ A, const unsigned short* __restrict__ Bw,
    const float* __restrict__ b_ih, const float* __restrict__ b_hh,
    const float* __restrict__ b1,
    float* __restrict__ gi, float* __restrict__ P1) {
  __shared__ __align__(16) unsigned short As[128*64];
  __shared__ __align__(16) unsigned short Bs[128*64];
  int tid = threadIdx.x;
  int rb = blockIdx.x >> 3, cb = blockIdx.x & 7;
  long row0 = (long)rb * 128;
  int n0 = cb * 128;
  int wv = tid >> 6, lane = tid & 63;
  int lq = lane >> 4, l16 = lane & 15;
  int wrg = wv & 3, wcg = wv >> 2;
  f32x4 acc[2][4];
#pragma unroll
  for (int i = 0; i < 2; ++i)
#pragma unroll
    for (int j = 0; j < 4; ++j) acc[i][j] = (f32x4){0.f,0.f,0.f,0.f};
  for (int kb = 0; kb < 256; kb += 64) {
#pragma unroll
    for (int i = 0; i < 2; ++i) {
      int s = i*512 + tid;
      int r = s >> 3, cg = (s & 7) ^ (r & 7);
      *(uint4*)&As[s*8] = *(const uint4*)&A[(row0 + r)*256 + kb + cg*8];
      *(uint4*)&Bs[s*8] = *(const uint4*)&Bw[(long)(n0 + r)*256 + kb + cg*8];
    }
    __syncthreads();
#pragma unroll
    for (int kc = 0; kc < 2; ++kc) {
      int csel = kc*4 + lq;
      bf16x8 af[2];
#pragma unroll
      for (int rt = 0; rt < 2; ++rt) {
        int r = wrg*32 + rt*16 + l16;
        af[rt] = *(const bf16x8*)&As[r*64 + ((csel ^ (r & 7)))*8];
      }
#pragma unroll
      for (int ct = 0; ct < 4; ++ct) {
        int n = wcg*64 + ct*16 + l16;
        bf16x8 bfr = *(const bf16x8*)&Bs[n*64 + ((csel ^ (n & 7)))*8];
        acc[0][ct] = __builtin_amdgcn_mfma_f32_16x16x32_bf16(af[0], bfr, acc[0][ct], 0, 0, 0);
        acc[1][ct] = __builtin_amdgcn_mfma_f32_16x16x32_bf16(af[1], bfr, acc[1][ct], 0, 0, 0);
      }
    }
    __syncthreads();
  }
#pragma unroll
  for (int rt = 0; rt < 2; ++rt)
#pragma unroll
    for (int q = 0; q < 4; ++q) {
      long row = row0 + wrg*32 + rt*16 + lq*4 + q;
#pragma unroll
      for (int ct = 0; ct < 4; ++ct) {
        int n = n0 + wcg*64 + ct*16 + l16;
        float v = acc[rt][ct][q];
        if (n < 512)      gi[row*G3 + n] = v + b_ih[n] + b_hh[n];
        else if (n < 768) gi[row*G3 + n] = v + b_ih[n];
        else              P1[row*256 + (n-768)] = v + b1[n-768];
      }
    }
}

// ---- persistent GRU (R14 best, 260 us): 256 blocks x 16 rows, 512 thr.
// Whh streams from L2 each step (compiler remats the loads; all residency
// attempts R7-R13 failed). ~70% of the per-XCD L2-BW bound. ----
__global__ __attribute__((amdgpu_flat_work_group_size(512, 512)))
__attribute__((amdgpu_waves_per_eu(2, 2)))
void k_gru(
    const float* __restrict__ z, const float* __restrict__ gi,
    const unsigned short* __restrict__ WhhB, const float* __restrict__ b_hh,
    const float* __restrict__ w0, unsigned short* __restrict__ hs) {
  __shared__ __align__(16) unsigned short hbf[2*16*256];  // two 8 KB buffers
  __shared__ __align__(16) float gis[768*20];             // gi^T, stride 20 fp32
  __shared__ __align__(16) float zs[64*16];               // z^T [t][row]
  __shared__ float wls[768 + 256];                        // w0 | b_hh n-gate
  int tid = threadIdx.x;
  int wv = tid >> 6, lane = tid & 63;
  int lq = lane >> 4, l16 = lane & 15;
  int row0 = blockIdx.x * 16;
  bf16x8 wf[6][8];
#pragma unroll
  for (int g = 0; g < 3; ++g)
#pragma unroll
    for (int tt = 0; tt < 2; ++tt)
#pragma unroll
      for (int ks = 0; ks < 8; ++ks)
        wf[g*2+tt][ks] = *(const bf16x8*)&WhhB[(long)(g*256 + wv*32 + tt*16 + l16)*256 + ks*32 + lq*8];
  for (int i = tid; i < 768; i += 512) wls[i] = w0[i];
  for (int i = tid; i < 256; i += 512) wls[768 + i] = b_hh[512 + i];
  for (int i = tid; i < 1024; i += 512) {
    int t = i >> 4, r = i & 15;
    zs[i] = z[(row0+r)*64 + t];
  }
#pragma unroll
  for (int i = 0; i < 24; ++i) {
    int s = i*512 + tid;
    int r = s / 768, cc = s - r*768;
    gis[cc*20 + r] = gi[(long)(row0+r)*768 + cc];
  }
  for (int i = tid; i < 2048; i += 512) ((unsigned int*)hbf)[i] = 0u;
  float hp[2][4] = {{0.f,0.f,0.f,0.f},{0.f,0.f,0.f,0.f}};
  const int s7 = l16 & 7;
  const int arow = l16*256;
  const int r4 = lq*4;
  const int hc0 = wv*32 + l16;
  const int cr = tid >> 5, ccc = tid & 31;
  const int csrc = cr*256 + ((ccc ^ (cr & 7)))*8;
  unsigned short* cbase = hs + (long)(row0+cr)*64*256 + ccc*8;
  __syncthreads();
#pragma unroll 1
  for (int t = 0; t < 64; ++t) {
    const int co = (t & 1) << 12;
    const int no = co ^ 4096;
    float zp[4];
    {
      float4 zv4 = *(const float4*)&zs[(t ? (t-1) : 0)*16 + r4];
#pragma unroll
      for (int q = 0; q < 4; ++q) zp[q] = t ? (&zv4.x)[q] : -1.0f;
    }
    f32x4 a[6];
#pragma unroll
    for (int tt = 0; tt < 2; ++tt) {
      int hc = hc0 + tt*16;
      f32x4 gR = *(const f32x4*)&gis[hc*20 + r4];
      f32x4 gU = *(const f32x4*)&gis[(256+hc)*20 + r4];
      float w0r = wls[hc], w0u = wls[256+hc], bn = wls[768 + hc];
#pragma unroll
      for (int q = 0; q < 4; ++q) {
        a[tt][q]   = gR[q] + zp[q]*w0r;
        a[2+tt][q] = gU[q] + zp[q]*w0u;
        a[4+tt][q] = bn;
      }
    }
#pragma unroll
    for (int ks = 0; ks < 8; ++ks) {
      bf16x8 af = *(const bf16x8*)&hbf[co + arow + (((ks*4+lq) ^ s7))*8];
#pragma unroll
      for (int f = 0; f < 6; ++f)
        a[f] = __builtin_amdgcn_mfma_f32_16x16x32_bf16(af, wf[f][ks], a[f], 0, 0, 0);
    }
    if (t) {
      uint4 cdat = *(const uint4*)&hbf[co + csrc];
      *(uint4*)(cbase + (t-1)*256) = cdat;
    }
#pragma unroll
    for (int tt = 0; tt < 2; ++tt) {
      int hc = hc0 + tt*16;
      int hchunk = hc >> 3, hlow = hc & 7;
      float w0n = wls[512 + hc];
      f32x4 gN = *(const f32x4*)&gis[(512+hc)*20 + r4];
#pragma unroll
      for (int q = 0; q < 4; ++q) {
        int r = r4 + q;
        float rr = sigm(a[tt][q]);
        float uu = sigm(a[2+tt][q]);
        float nn = tanh_fast(gN[q] + zp[q]*w0n + rr*a[4+tt][q]);
        float hn = uu*(hp[tt][q] - nn) + nn;
        hp[tt][q] = hn;
        hbf[no + r*256 + ((hchunk ^ (r & 7)))*8 + hlow] = f2bf(hn);
      }
    }
    __syncthreads();
  }
  uint4 cdat = *(const uint4*)&hbf[0 + csrc];
  *(uint4*)(cbase + 63*256) = cdat;
}

// ---- MLP layer 1, in-place: Out = tanh(A @ W1a^T + P1[row>>6]) ----
__global__ __launch_bounds__(512) void k_l1(
    const unsigned short* __restrict__ A, const unsigned short* __restrict__ Bw,
    const float* __restrict__ P1, unsigned short* __restrict__ Out) {
  __shared__ __align__(16) unsigned short As[128*64];
  __shared__ __align__(16) unsigned short Bs[256*64];
  int tid = threadIdx.x;
  long row0 = (long)blockIdx.x * 128;
  int wv = tid >> 6, lane = tid & 63;
  int lq = lane >> 4, l16 = lane & 15;
  int wrg = wv & 3, wcg = wv >> 2;
  f32x4 acc[2][8];
#pragma unroll
  for (int i = 0; i < 2; ++i)
#pragma unroll
    for (int j = 0; j < 8; ++j) acc[i][j] = (f32x4){0.f,0.f,0.f,0.f};
  for (int kb = 0; kb < 256; kb += 64) {
#pragma unroll
    for (int i = 0; i < 2; ++i) {
      int s = i*512 + tid;
      int r = s >> 3, cg = (s & 7) ^ (r & 7);
      *(uint4*)&As[s*8] = *(const uint4*)&A[(row0 + r)*256 + kb + cg*8];
    }
#pragma unroll
    for (int i = 0; i < 4; ++i) {
      int s = i*512 + tid;
      int r = s >> 3, cg = (s & 7) ^ (r & 7);
      *(uint4*)&Bs[s*8] = *(const uint4*)&Bw[(long)r*256 + kb + cg*8];
    }
    __syncthreads();
#pragma unroll
    for (int kc = 0; kc < 2; ++kc) {
      int csel = kc*4 + lq;
      bf16x8 af[2];
#pragma unroll
      for (int rt = 0; rt < 2; ++rt) {
        int r = wrg*32 + rt*16 + l16;
        af[rt] = *(const bf16x8*)&As[r*64 + ((csel ^ (r & 7)))*8];
      }
#pragma unroll
      for (int ct = 0; ct < 8; ++ct) {
        int n = wcg*128 + ct*16 + l16;
        bf16x8 bfr = *(const bf16x8*)&Bs[n*64 + ((csel ^ (n & 7)))*8];
        acc[0][ct] = __builtin_amdgcn_mfma_f32_16x16x32_bf16(af[0], bfr, acc[0][ct], 0, 0, 0);
        acc[1][ct] = __builtin_amdgcn_mfma_f32_16x16x32_bf16(af[1], bfr, acc[1][ct], 0, 0, 0);
      }
    }
    __syncthreads();
  }
#pragma unroll
  for (int rt = 0; rt < 2; ++rt)
#pragma unroll
    for (int q = 0; q < 4; ++q) {
      long row = row0 + wrg*32 + rt*16 + lq*4 + q;
#pragma unroll
      for (int ct = 0; ct < 8; ++ct) {
        int n = wcg*128 + ct*16 + l16;
        float b = P1[(row >> 6)*256 + n];
        Out[row*256 + n] = f2bf(tanh_fast(acc[rt][ct][q] + b));
      }
    }
}

// ---- fused MLP layer2 + layer3 + mixture likelihood ----
__global__ __launch_bounds__(512) void k_l23(
    const unsigned short* __restrict__ A, const unsigned short* __restrict__ W2B,
    const float* __restrict__ b2, const unsigned short* __restrict__ W3pB,
    const float* __restrict__ b3, const float* __restrict__ z,
    float* __restrict__ ll) {
  __shared__ __align__(16) unsigned short As[128*64];
  __shared__ __align__(16) unsigned short Bs[256*64];
  __shared__ __align__(16) unsigned short h2s[128*256];
  int tid = threadIdx.x;
  long row0 = (long)blockIdx.x * 128;
  int wv = tid >> 6, lane = tid & 63;
  int lq = lane >> 4, l16 = lane & 15;
  int wrg = wv & 3, wcg = wv >> 2;
  f32x4 acc[2][8];
#pragma unroll
  for (int i = 0; i < 2; ++i)
#pragma unroll
    for (int j = 0; j < 8; ++j) acc[i][j] = (f32x4){0.f,0.f,0.f,0.f};
  for (int kb = 0; kb < 256; kb += 64) {
#pragma unroll
    for (int i = 0; i < 2; ++i) {
      int s = i*512 + tid;
      int r = s >> 3, cg = (s & 7) ^ (r & 7);
      *(uint4*)&As[s*8] = *(const uint4*)&A[(row0 + r)*256 + kb + cg*8];
    }
#pragma unroll
    for (int i = 0; i < 4; ++i) {
      int s = i*512 + tid;
      int r = s >> 3, cg = (s & 7) ^ (r & 7);
      *(uint4*)&Bs[s*8] = *(const uint4*)&W2B[(long)r*256 + kb + cg*8];
    }
    __syncthreads();
#pragma unroll
    for (int kc = 0; kc < 2; ++kc) {
      int csel = kc*4 + lq;
      bf16x8 af[2];
#pragma unroll
      for (int rt = 0; rt < 2; ++rt) {
        int r = wrg*32 + rt*16 + l16;
        af[rt] = *(const bf16x8*)&As[r*64 + ((csel ^ (r & 7)))*8];
      }
#pragma unroll
      for (int ct = 0; ct < 8; ++ct) {
        int n = wcg*128 + ct*16 + l16;
        bf16x8 bfr = *(const bf16x8*)&Bs[n*64 + ((csel ^ (n & 7)))*8];
        acc[0][ct] = __builtin_amdgcn_mfma_f32_16x16x32_bf16(af[0], bfr, acc[0][ct], 0, 0, 0);
        acc[1][ct] = __builtin_amdgcn_mfma_f32_16x16x32_bf16(af[1], bfr, acc[1][ct], 0, 0, 0);
      }
    }
    __syncthreads();
  }
  // h2 -> LDS (bf16, swizzled for A-side reads)
#pragma unroll
  for (int rt = 0; rt < 2; ++rt)
#pragma unroll
    for (int q = 0; q < 4; ++q) {
      int lr = wrg*32 + rt*16 + lq*4 + q;
#pragma unroll
      for (int ct = 0; ct < 8; ++ct) {
        int n = wcg*128 + ct*16 + l16;
        h2s[lr*256 + (((n >> 3) ^ swz(lr))*8 + (n & 7))] =
            f2bf(tanh_fast(acc[rt][ct][q] + b2[n]));
      }
    }
  // stage W3p into Bs (64 x 256), swizzled
#pragma unroll
  for (int i = 0; i < 4; ++i) {
    int s = i*512 + tid;
    int r = s >> 5, cc = s & 31;
    *(uint4*)&Bs[r*256 + ((cc ^ swz(r)))*8] = *(const uint4*)&W3pB[r*256 + cc*8];
  }
  __syncthreads();
  // stage 2: each wave computes its own 16 rows x 64 params
  f32x4 pacc[4];
#pragma unroll
  for (int j = 0; j < 4; ++j) pacc[j] = (f32x4){0.f,0.f,0.f,0.f};
#pragma unroll
  for (int ks = 0; ks < 8; ++ks) {
    int chunk = ks*4 + lq;
    int ar = wv*16 + l16;
    bf16x8 af = *(const bf16x8*)&h2s[ar*256 + ((chunk ^ swz(ar)))*8];
#pragma unroll
    for (int ct = 0; ct < 4; ++ct) {
      int br = ct*16 + l16;
      bf16x8 bfr = *(const bf16x8*)&Bs[br*256 + ((chunk ^ swz(br)))*8];
      pacc[ct] = __builtin_amdgcn_mfma_f32_16x16x32_bf16(af, bfr, pacc[ct], 0, 0, 0);
    }
  }
  // params to own LDS region (reuse h2s rows of this wave), stride 68 fp32
  float* Ps = (float*)&h2s[wv*16*256];
#pragma unroll
  for (int ct = 0; ct < 4; ++ct) {
    int n = ct*16 + l16;
    float b = (n < 60) ? b3[n] : 0.0f;
#pragma unroll
    for (int q = 0; q < 4; ++q)
      Ps[(lq*4 + q)*68 + n] = pacc[ct][q] + b;
  }
  // per-row likelihood (wave-internal)
  if (lane < 16) {
    long grow = row0 + wv*16 + lane;
    float zv = z[grow];
    const float* p = &Ps[lane*68];
    float mx1 = -1e30f;
#pragma unroll
    for (int i = 0; i < NK; ++i) mx1 = fmaxf(mx1, p[i]);
    float s1 = 0.0f;
#pragma unroll
    for (int i = 0; i < NK; ++i) s1 += __expf(p[i] - mx1);
    float lse1 = mx1 + __logf(s1);
    float a[NK];
    float mx2 = -1e30f;
#pragma unroll
    for (int i = 0; i < NK; ++i) {
      float lg = p[i], me = p[20+i], ls = p[40+i];
      float e = __expf(-ls);
      float d = (zv - me) * e;
      float ai = -0.5f*d*d - ls - 0.5f*LOG2PI + lg;
      a[i] = ai;
      mx2 = fmaxf(mx2, ai);
    }
    float s2 = 0.0f;
#pragma unroll
    for (int i = 0; i < NK; ++i) s2 += __expf(a[i] - mx2);
    float lse2 = mx2 + __logf(s2);
    ll[grow] = lse2 - lse1;
  }
}

// out[b] = sum_{t < S_b} ll[b,t]
__global__ __launch_bounds__(256) void k_final(const float* __restrict__ bv,
    const float* __restrict__ mv, const float* __restrict__ ll,
    float* __restrict__ out) {
  int tid = threadIdx.x;
  int wave = tid >> 6, lane = tid & 63;
  int b = blockIdx.x*4 + wave;
  float q = mv[b*64 + lane] * (1.0f - bv[b*64 + lane]);
  unsigned long long bal = __ballot(q > 0.5f);
  int S = __popcll(bal);
  float val = (lane < S) ? ll[(long)b*64 + lane] : 0.0f;
#pragma unroll
  for (int off = 32; off > 0; off >>= 1) val += __shfl_down(val, off);
  if (lane == 0) out[b] = val;
}

extern "C" void kernel_launch(void* const* d_in, const int* in_sizes, int n_in,
                              void* d_out, int out_size, void* d_ws, size_t ws_size,
                              hipStream_t stream) {
  const float* z    = (const float*)d_in[0];
  const float* c    = (const float*)d_in[1];
  const float* bv   = (const float*)d_in[2];
  const float* mv   = (const float*)d_in[3];
  const float* W_ih = (const float*)d_in[4];
  const float* W_hh = (const float*)d_in[5];
  const float* b_ih = (const float*)d_in[6];
  const float* b_hh = (const float*)d_in[7];
  const float* W1   = (const float*)d_in[8];
  const float* b1   = (const float*)d_in[9];
  const float* W2   = (const float*)d_in[10];
  const float* b2   = (const float*)d_in[11];
  const float* W3   = (const float*)d_in[12];
  const float* b3   = (const float*)d_in[13];
  float* out = (float*)d_out;

  char* p = (char*)d_ws;
  auto alloc = [&](size_t bytes) {
    char* q = p;
    p += (bytes + 255) & ~(size_t)255;
    return q;
  };
  unsigned short* cbmB = (unsigned short*)alloc((size_t)BATCH*256*2);
  unsigned short* CW   = (unsigned short*)alloc((size_t)1024*256*2);
  unsigned short* WhhB = (unsigned short*)alloc((size_t)G3*256*2);
  unsigned short* W1aB = (unsigned short*)alloc((size_t)256*256*2);
  unsigned short* W2B  = (unsigned short*)alloc((size_t)256*256*2);
  unsigned short* W3pB = (unsigned short*)alloc((size_t)64*256*2);
  float* w0 = (float*)alloc((size_t)G3*4);
  float* gi = (float*)alloc((size_t)BATCH*G3*4);
  float* P1 = (float*)alloc((size_t)BATCH*256*4);
  float* ll = (float*)alloc((size_t)NROW*4);
  unsigned short* hs = (unsigned short*)alloc((size_t)NROW*HDIM*2);

  k_cvtall<<<6468, 256, 0, stream>>>(c, bv, mv, W_ih, W_hh, W1, W2, W3,
                                     cbmB, CW, WhhB, W1aB, W2B, W3pB, w0);
  k_pre<<<256, 512, 0, stream>>>(cbmB, CW, b_ih, b_hh, b1, gi, P1);
  k_gru<<<256, 512, 0, stream>>>(z, gi, WhhB, b_hh, w0, hs);
  k_l1<<<NROW/128, 512, 0, stream>>>(hs, W1aB, P1, hs);
  k_l23<<<NROW/128, 512, 0, stream>>>(hs, W2B, b2, W3pB, b3, z, ll);
  k_final<<<BATCH/4, 256, 0, stream>>>(bv, mv, ll, out);
}